// Round 11
// baseline (276.831 us; speedup 1.0000x reference)
//
#include <hip/hip_runtime.h>
#include <cstdint>
#include <cstddef>

typedef unsigned short u16;
typedef unsigned int   u32;

typedef short bf16x8 __attribute__((ext_vector_type(8)));
typedef float f32x4  __attribute__((ext_vector_type(4)));

// ---------------- helpers ----------------
__device__ __forceinline__ u16 f2bf(float f) {   // RNE f32 -> bf16
  u32 u = __float_as_uint(f);
  u += 0x7fffu + ((u >> 16) & 1u);
  return (u16)(u >> 16);
}
__device__ __forceinline__ float bflo(u32 w) { return __uint_as_float((w & 0xffffu) << 16); }
__device__ __forceinline__ float bfhi(u32 w) { return __uint_as_float(w & 0xffff0000u); }

#define GLB_AS(p) ((const __attribute__((address_space(1))) void*)(p))
#define LDS_AS(p) ((__attribute__((address_space(3))) void*)(p))

// ---------------- f32 -> bf16 convert: Wi + Wo ONLY (R17) --------------------
// A-conversion fused into gemm1 (reads inputs f32 directly). 262144 quads
// -> 1024 blocks x 256 exactly.
__global__ __launch_bounds__(256)
void conv2_f32_bf16(const float* __restrict__ wi, u16* __restrict__ wib,
                    const float* __restrict__ wo, u16* __restrict__ wob)
{
  long i = (long)blockIdx.x * 256 + threadIdx.x;
  const float* src; u16* dst;
  if (i < 131072L) { src = wi; dst = wib; }
  else { i -= 131072L; src = wo; dst = wob; }
  float4 v = ((const float4*)src)[i];
  u32 lo = (u32)f2bf(v.x) | ((u32)f2bf(v.y) << 16);
  u32 hi = (u32)f2bf(v.z) | ((u32)f2bf(v.w) << 16);
  ((uint2*)dst)[i] = make_uint2(lo, hi);
}

// ---------------- gemm1: A = f32 source, converted in-kernel (R17) ----------
// C[m,n] = sum_k A[m,k]*W[n,k]; A f32 MxK row-major, W bf16 NxK row-major.
// 256x128 tile, BK=32, 512 thr, 8 waves 64x64, validated R2 fragment maps.
// A staged via regs: thread handles granules g = {tid, 512+tid}; granule g
// holds rows r=g>>2, octet o=(g&3)^((r>>1)&3) -- byte-identical LDS image
// to the validated DMA path (o == the koff the DMA fetched). B stays on
// global_load_lds. 2-buffer R8 skeleton (48.5us measured), 2 barriers/step:
// { issue A-loads(t+1)+B-DMA(t+1) ; compute(t) ; sync (drains vmem) ;
//   convert+ds_write A(t+1) ; sync }.
template<int N, int K, int LOGNB>
__global__ __launch_bounds__(512, 4)
void gemm_w1f(const float* __restrict__ Af, const u16* __restrict__ Bw,
              const float* __restrict__ bias, u16* __restrict__ Cout)
{
  __shared__ __align__(16) u16 As[2][256 * 32];   // 2 x 16 KB
  __shared__ __align__(16) u16 Bs[2][128 * 32];   // 2 x  8 KB  (48 KB)

  const int tid  = threadIdx.x;
  const int lane = tid & 63;
  const int wave = tid >> 6;
  const int bid  = blockIdx.x;
  const int xcd  = bid & 7;
  const int s    = bid >> 3;
  const int m0 = (xcd * 16 + (s >> LOGNB)) * 256;
  const int n0 = (s & ((1 << LOGNB) - 1)) * 128;
  const int wm = (wave & 3) * 64;
  const int wn = (wave >> 2) * 64;

  f32x4 acc[4][4];
#pragma unroll
  for (int i = 0; i < 4; ++i)
#pragma unroll
    for (int j = 0; j < 4; ++j) acc[i][j] = f32x4{0.f, 0.f, 0.f, 0.f};

  // A reg-staging addressing (granule = 8 bf16 = 8 f32 source)
  const float* Asrc[2]; int gIdx[2];
#pragma unroll
  for (int i = 0; i < 2; ++i) {
    int g = i * 512 + tid;
    int r = g >> 2;
    int o = (g & 3) ^ ((r >> 1) & 3);
    Asrc[i] = Af + (size_t)(m0 + r) * K + o * 8;
    gIdx[i] = g;
  }
  // B DMA (validated path)
  const u16* Bp; int ldsB;
  {
    int g = tid;
    int r = g >> 2;
    int koff = ((g & 3) ^ ((r >> 1) & 3)) << 3;
    Bp   = Bw + (size_t)(n0 + r) * K + koff;
    ldsB = (wave * 64) * 8;
  }

  // fragment granule offsets (R2-validated map)
  const int fm = lane & 15;
  const int q  = lane >> 4;
  int aoff[4], boff[4];
#pragma unroll
  for (int i = 0; i < 4; ++i) {
    int m = wm + i * 16 + fm;
    aoff[i] = (m * 4 + (q ^ ((m >> 1) & 3))) * 8;
    int n = wn + i * 16 + fm;
    boff[i] = (n * 4 + (q ^ ((n >> 1) & 3))) * 8;
  }

  float4 ar[2][2];   // [granule][lo/hi 4 floats]
  auto loadA = [&](int kt) {
#pragma unroll
    for (int i = 0; i < 2; ++i) {
      ar[i][0] = *(const float4*)(Asrc[i] + kt);
      ar[i][1] = *(const float4*)(Asrc[i] + kt + 4);
    }
  };
  auto writeA = [&](int buf) {
#pragma unroll
    for (int i = 0; i < 2; ++i) {
      uint4 w;
      w.x = (u32)f2bf(ar[i][0].x) | ((u32)f2bf(ar[i][0].y) << 16);
      w.y = (u32)f2bf(ar[i][0].z) | ((u32)f2bf(ar[i][0].w) << 16);
      w.z = (u32)f2bf(ar[i][1].x) | ((u32)f2bf(ar[i][1].y) << 16);
      w.w = (u32)f2bf(ar[i][1].z) | ((u32)f2bf(ar[i][1].w) << 16);
      *(uint4*)&As[buf][gIdx[i] * 8] = w;
    }
  };
  auto stageB = [&](int buf, int kt) {
    __builtin_amdgcn_global_load_lds(GLB_AS(Bp + kt), LDS_AS(&Bs[buf][ldsB]), 16, 0, 0);
  };
  auto compute = [&](int buf) {
    bf16x8 af[4], bfr[4];
#pragma unroll
    for (int i = 0; i < 4; ++i) { af[i]  = *(const bf16x8*)&As[buf][aoff[i]];
                                  bfr[i] = *(const bf16x8*)&Bs[buf][boff[i]]; }
#pragma unroll
    for (int mi = 0; mi < 4; ++mi)
#pragma unroll
      for (int ni = 0; ni < 4; ++ni)
        acc[mi][ni] = __builtin_amdgcn_mfma_f32_16x16x32_bf16(af[mi], bfr[ni],
                                                              acc[mi][ni], 0, 0, 0);
  };

  constexpr int NT = K / 32;
  // prologue: tile 0
  loadA(0); stageB(0, 0);
  __syncthreads();                 // A-regs + B(0) landed (vmcnt drain)
  writeA(0);
  __syncthreads();                 // As[0] visible
  int buf = 0;
  for (int t = 0; t < NT; ++t) {
    const bool pre = (t + 1 < NT);
    if (pre) { loadA((t + 1) * 32); stageB(buf ^ 1, (t + 1) * 32); }
    compute(buf);                  // prefetch latency hides under MFMA
    __syncthreads();               // compute done; A-regs + B(t+1) landed
    if (pre) writeA(buf ^ 1);
    __syncthreads();               // As[buf^1] visible
    buf ^= 1;
  }

  // epilogue: C/D layout col=lane&15, row=(lane>>4)*4+reg  (validated)
  const int colL = lane & 15;
  const int rowQ = (lane >> 4) * 4;
#pragma unroll
  for (int mi = 0; mi < 4; ++mi) {
#pragma unroll
    for (int ni = 0; ni < 4; ++ni) {
      int col  = n0 + wn + ni * 16 + colL;
      int rowb = m0 + wm + mi * 16 + rowQ;
      float bv = bias[col];
#pragma unroll
      for (int r = 0; r < 4; ++r) {
        float v = acc[mi][ni][r] + bv;
        size_t idx = (size_t)(rowb + r) * N + col;
        Cout[idx] = f2bf(v);
      }
    }
  }
}

// ---------------- gemm2: bf16 A, validated R3/R9 kernel (unchanged) ---------
template<int N, int K, int LOGNB, int OUT_BF16, int RELU>
__global__ __launch_bounds__(512, 4)
void gemm_w2(const u16* __restrict__ A, const u16* __restrict__ Bw,
             const float* __restrict__ bias, void* __restrict__ Cout)
{
  __shared__ __align__(16) u16 As[3][256 * 32];   // 3 x 16 KB
  __shared__ __align__(16) u16 Bs[3][128 * 32];   // 3 x  8 KB  (72 KB total)

  const int tid  = threadIdx.x;
  const int lane = tid & 63;
  const int wave = tid >> 6;
  const int bid  = blockIdx.x;
  const int xcd  = bid & 7;
  const int s    = bid >> 3;
  const int m0 = (xcd * 16 + (s >> LOGNB)) * 256;
  const int n0 = (s & ((1 << LOGNB) - 1)) * 128;
  const int wm = (wave & 3) * 64;
  const int wn = (wave >> 2) * 64;

  f32x4 acc[4][4];
#pragma unroll
  for (int i = 0; i < 4; ++i)
#pragma unroll
    for (int j = 0; j < 4; ++j) acc[i][j] = f32x4{0.f, 0.f, 0.f, 0.f};

  const u16* Ap[2]; const u16* Bp; int ldsA[2]; int ldsB;
#pragma unroll
  for (int i = 0; i < 2; ++i) {
    int g = i * 512 + tid;
    int r = g >> 2;
    int koff = ((g & 3) ^ ((r >> 1) & 3)) << 3;
    Ap[i]   = A + (size_t)(m0 + r) * K + koff;
    ldsA[i] = (i * 512 + wave * 64) * 8;        // wave-uniform base (u16)
  }
  {
    int g = tid;
    int r = g >> 2;
    int koff = ((g & 3) ^ ((r >> 1) & 3)) << 3;
    Bp   = Bw + (size_t)(n0 + r) * K + koff;
    ldsB = (wave * 64) * 8;
  }

  const int fm = lane & 15;
  const int q  = lane >> 4;
  int aoff[4], boff[4];
#pragma unroll
  for (int i = 0; i < 4; ++i) {
    int m = wm + i * 16 + fm;
    aoff[i] = (m * 4 + (q ^ ((m >> 1) & 3))) * 8;
    int n = wn + i * 16 + fm;
    boff[i] = (n * 4 + (q ^ ((n >> 1) & 3))) * 8;
  }

  auto stage = [&](int buf, int kt) {
    __builtin_amdgcn_global_load_lds(GLB_AS(Ap[0] + kt), LDS_AS(&As[buf][ldsA[0]]), 16, 0, 0);
    __builtin_amdgcn_global_load_lds(GLB_AS(Ap[1] + kt), LDS_AS(&As[buf][ldsA[1]]), 16, 0, 0);
    __builtin_amdgcn_global_load_lds(GLB_AS(Bp    + kt), LDS_AS(&Bs[buf][ldsB]),    16, 0, 0);
  };
  auto compute = [&](int buf) {
    bf16x8 af[4], bfr[4];
#pragma unroll
    for (int i = 0; i < 4; ++i) { af[i]  = *(const bf16x8*)&As[buf][aoff[i]];
                                  bfr[i] = *(const bf16x8*)&Bs[buf][boff[i]]; }
#pragma unroll
    for (int mi = 0; mi < 4; ++mi)
#pragma unroll
      for (int ni = 0; ni < 4; ++ni)
        acc[mi][ni] = __builtin_amdgcn_mfma_f32_16x16x32_bf16(af[mi], bfr[ni],
                                                              acc[mi][ni], 0, 0, 0);
  };

  constexpr int NT = K / 32;
  stage(0, 0);
  stage(1, 32);                       // depth-2 prefetch in flight
#pragma unroll
  for (int t = 0; t < NT - 1; ++t) {
    asm volatile("s_waitcnt vmcnt(3)" ::: "memory");
    __builtin_amdgcn_s_barrier();     // all waves' tile-t DMA landed; t-1 reads done
    if (t + 2 < NT) stage((t + 2) % 3, (t + 2) * 32);
    compute(t % 3);
  }
  asm volatile("s_waitcnt vmcnt(0)" ::: "memory");
  __builtin_amdgcn_s_barrier();
  compute((NT - 1) % 3);

  const int colL = lane & 15;
  const int rowQ = (lane >> 4) * 4;
#pragma unroll
  for (int mi = 0; mi < 4; ++mi) {
#pragma unroll
    for (int ni = 0; ni < 4; ++ni) {
      int col  = n0 + wn + ni * 16 + colL;
      int rowb = m0 + wm + mi * 16 + rowQ;
      float bv = bias[col];
#pragma unroll
      for (int r = 0; r < 4; ++r) {
        float v = acc[mi][ni][r] + bv;
        if (RELU) v = fmaxf(v, 0.f);
        size_t idx = (size_t)(rowb + r) * N + col;
        if (OUT_BF16) ((u16*)Cout)[idx] = f2bf(v);
        else          ((float*)Cout)[idx] = v;
      }
    }
  }
}

// ---------------- scan pass 1: per-chunk end state (R6-validated) ----------
__global__ __launch_bounds__(256)
void scan_chunk_end(const u16* __restrict__ u, const float* __restrict__ plog,
                    float2* __restrict__ e)
{
  const int t = threadIdx.x;          // channel pair 2t, 2t+1
  const int c = blockIdx.x;           // chunk 0..127 (32 steps each)
  const int b = blockIdx.y;
  float2 vl = ((const float2*)plog)[t];
  float2 tl = ((const float2*)plog)[256 + t];
  float v0 = expf(vl.x), v1 = expf(vl.y);
  float t0 = expf(tl.x), t1 = expf(tl.y);
  float m0 = expf(-v0), m1 = expf(-v1);
  float lr0 = m0 * cosf(t0), li0 = m0 * sinf(t0);
  float lr1 = m1 * cosf(t1), li1 = m1 * sinf(t1);
  const uint2* up = (const uint2*)u;            // 256 uint2 per row
  size_t idx = (size_t)(b * 4096 + c * 32) * 256 + t;
  float h0r = 0.f, h0i = 0.f, h1r = 0.f, h1i = 0.f;
#pragma unroll 8
  for (int s = 0; s < 32; ++s) {
    uint2 w = up[idx]; idx += 256;
    float u0r = bflo(w.x), u0i = bfhi(w.x);
    float u1r = bflo(w.y), u1i = bfhi(w.y);
    float n0r = fmaf(lr0, h0r, fmaf(-li0, h0i, u0r));
    float n0i = fmaf(lr0, h0i, fmaf( li0, h0r, u0i));
    float n1r = fmaf(lr1, h1r, fmaf(-li1, h1i, u1r));
    float n1i = fmaf(lr1, h1i, fmaf( li1, h1r, u1i));
    h0r = n0r; h0i = n0i; h1r = n1r; h1i = n1i;
  }
  ((float4*)e)[(size_t)(b * 128 + c) * 256 + t] = make_float4(h0r, h0i, h1r, h1i);
}

// ---------------- scan pass 1.5: in-place prefix (R6-validated) -------------
__global__ __launch_bounds__(256)
void scan_mid(const float* __restrict__ plog, float4* __restrict__ e)
{
  const int t = threadIdx.x;              // 0..255, channels 2t,2t+1
  const int b = blockIdx.x;               // batch 0..7
  float2 vl = ((const float2*)plog)[t];
  float2 tl = ((const float2*)plog)[256 + t];
  float v0 = expf(vl.x), v1 = expf(vl.y);
  float t0 = expf(tl.x), t1 = expf(tl.y);
  float Lm0 = expf(-32.f * v0), Lm1 = expf(-32.f * v1);
  float La0 = 32.f * t0,        La1 = 32.f * t1;
  float Lr0 = Lm0 * cosf(La0), Li0 = Lm0 * sinf(La0);
  float Lr1 = Lm1 * cosf(La1), Li1 = Lm1 * sinf(La1);
  float h0r = 0.f, h0i = 0.f, h1r = 0.f, h1i = 0.f;
  size_t base = (size_t)(b * 128) * 256 + t;    // float4 index, row stride 256
#pragma unroll 4
  for (int c = 0; c < 128; ++c) {
    float4 ec = e[base + (size_t)c * 256];
    float n0r = fmaf(Lr0, h0r, fmaf(-Li0, h0i, ec.x));
    float n0i = fmaf(Lr0, h0i, fmaf( Li0, h0r, ec.y));
    float n1r = fmaf(Lr1, h1r, fmaf(-Li1, h1i, ec.z));
    float n1i = fmaf(Lr1, h1i, fmaf( Li1, h1r, ec.w));
    h0r = n0r; h0i = n0i; h1r = n1r; h1i = n1i;
    e[base + (size_t)c * 256] = make_float4(h0r, h0i, h1r, h1i);
  }
}

// ---------------- scan pass 2 (carry lookup + output, R6-validated) ---------
__global__ __launch_bounds__(256)
void scan_out2(const u16* __restrict__ u, const float* __restrict__ plog,
               const float4* __restrict__ e, u16* __restrict__ xr)
{
  const int t = threadIdx.x;          // channel pair 2t, 2t+1
  const int c = blockIdx.x;
  const int b = blockIdx.y;
  float2 vl = ((const float2*)plog)[t];
  float2 tl = ((const float2*)plog)[256 + t];
  float2 gl = ((const float2*)plog)[512 + t];
  float v0 = expf(vl.x), v1 = expf(vl.y);
  float t0 = expf(tl.x), t1 = expf(tl.y);
  float g0 = expf(gl.x), g1 = expf(gl.y);
  float m0 = expf(-v0), m1 = expf(-v1);
  float lr0 = m0 * cosf(t0), li0 = m0 * sinf(t0);
  float lr1 = m1 * cosf(t1), li1 = m1 * sinf(t1);

  float h0r = 0.f, h0i = 0.f, h1r = 0.f, h1i = 0.f;
  if (c > 0) {
    float4 ec = e[(size_t)(b * 128 + c - 1) * 256 + t];
    h0r = ec.x; h0i = ec.y; h1r = ec.z; h1i = ec.w;
  }

  const uint2* up = (const uint2*)u;
  u32* xp = (u32*)xr;                 // 512 u32 per output row of 1024 u16
  size_t uidx = (size_t)(b * 4096 + c * 32) * 256 + t;
  size_t xidx = (size_t)(b * 4096 + c * 32) * 512 + t;
#pragma unroll 8
  for (int s = 0; s < 32; ++s) {
    uint2 w = up[uidx]; uidx += 256;
    float u0r = bflo(w.x), u0i = bfhi(w.x);
    float u1r = bflo(w.y), u1i = bfhi(w.y);
    float n0r = fmaf(lr0, h0r, fmaf(-li0, h0i, u0r));
    float n0i = fmaf(lr0, h0i, fmaf( li0, h0r, u0i));
    float n1r = fmaf(lr1, h1r, fmaf(-li1, h1i, u1r));
    float n1i = fmaf(lr1, h1i, fmaf( li1, h1r, u1i));
    h0r = n0r; h0i = n0i; h1r = n1r; h1i = n1i;
    xp[xidx]       = (u32)f2bf(g0 * h0r) | ((u32)f2bf(g1 * h1r) << 16);
    xp[xidx + 256] = (u32)f2bf(g0 * h0i) | ((u32)f2bf(g1 * h1i) << 16);
    xidx += 512;
  }
}

// ---------------- launch ----------------
extern "C" void kernel_launch(void* const* d_in, const int* in_sizes, int n_in,
                              void* d_out, int out_size, void* d_ws, size_t ws_size,
                              hipStream_t stream)
{
  (void)in_sizes; (void)n_in; (void)out_size; (void)ws_size;
  const float* inputs = (const float*)d_in[0];
  const float* Wi     = (const float*)d_in[1];
  const float* bi     = (const float*)d_in[2];
  const float* Wo     = (const float*)d_in[3];
  const float* bo     = (const float*)d_in[4];
  const float* plog   = (const float*)d_in[5];

  char* ws = (char*)d_ws;
  u16*    xrA   = (u16*)(ws);                        // xr_bf (64 MB)
  u16*    u_bf  = (u16*)(ws + 67108864ull);          // 64 MB
  u16*    Wi_bf = (u16*)(ws + 134217728ull);         // 1 MB
  u16*    Wo_bf = (u16*)(ws + 135266304ull);         // 1 MB
  float2* e_b   = (float2*)(ws + 136314880ull);      // 4 MB (8 x 128 x 512 float2)

  // 1) convert Wi/Wo to bf16 (tiny; A-conversion fused into gemm1)
  conv2_f32_bf16<<<1024, 256, 0, stream>>>(Wi, Wi_bf, Wo, Wo_bf);

  // 2) u = X @ Wi^T + bi   (M=32768, N=1024, K=512), f32 A in-kernel convert
  //    128 m-tiles (16/XCD) x 8 n-tiles = 1024 blocks of 256x128
  gemm_w1f<1024, 512, 3><<<1024, 512, 0, stream>>>(inputs, Wi_bf, bi, u_bf);

  // 3) chunked complex prefix scan + gamma, write xr (bf16)
  scan_chunk_end<<<dim3(128, 8), 256, 0, stream>>>(u_bf, plog, e_b);
  scan_mid<<<8, 256, 0, stream>>>(plog, (float4*)e_b);
  scan_out2<<<dim3(128, 8), 256, 0, stream>>>(u_bf, plog, (const float4*)e_b, xrA);

  // 4) out = relu(xr @ Wo^T + bo)  (M=32768, N=512, K=1024), fp32 out
  //    128 m-tiles (16/XCD) x 4 n-tiles = 512 blocks of 256x128
  gemm_w2<512, 1024, 2, 0, 1><<<512, 512, 0, stream>>>(xrA, Wo_bf, bo, d_out);
}